// Round 2
// baseline (324.680 us; speedup 1.0000x reference)
//
#include <hip/hip_runtime.h>
#include <stdint.h>

#define N_ 256
#define H_ 1024
#define BS_ 128

__global__ __launch_bounds__(256) void manifold_fused(
    const float* __restrict__ x,
    const float* __restrict__ Wf1, const float* __restrict__ bf1v,
    const float* __restrict__ Wf2, const float* __restrict__ bf2v,
    const float* __restrict__ Wg1, const float* __restrict__ bg1v,
    const float* __restrict__ Wg2, const float* __restrict__ bg2v,
    const float* __restrict__ Wk1, const float* __restrict__ bk1v,
    const float* __restrict__ Wk2, const float* __restrict__ bk2v,
    float* __restrict__ out)
{
    const int b = blockIdx.x;
    const int t = threadIdx.x;

    __shared__ float xs[N_];
    __shared__ float tf[H_], tg[H_], tk[H_], sk[H_];
    __shared__ float fo[N_], go[N_];
    __shared__ float sfv[H_], sgv[H_];
    __shared__ float red[12];

    // ---- stage x row -------------------------------------------------------
    xs[t] = x[b * N_ + t];
    __syncthreads();

    // ---- layer 1 of all 3 MLPs: z[h] = x . W1[h,:] + b1[h] -----------------
    // thread t owns h = t + 256*m, m = 0..3, for each of f/g/k
    {
        float acc[12];
        const float4* rows[12];
        #pragma unroll
        for (int m = 0; m < 4; ++m) {
            const int h = t + m * 256;
            rows[m]     = (const float4*)(Wf1 + h * N_);
            rows[4 + m] = (const float4*)(Wg1 + h * N_);
            rows[8 + m] = (const float4*)(Wk1 + h * N_);
            acc[m]      = bf1v[h];
            acc[4 + m]  = bg1v[h];
            acc[8 + m]  = bk1v[h];
        }
        const float4* xs4 = (const float4*)xs;
        #pragma unroll 2
        for (int c = 0; c < 64; ++c) {          // 4 elements per chunk
            float4 a = xs4[c];
            #pragma unroll
            for (int r = 0; r < 12; ++r) {
                float4 w = rows[r][c];
                acc[r] += w.x * a.x + w.y * a.y + w.z * a.z + w.w * a.w;
            }
        }
        #pragma unroll
        for (int m = 0; m < 4; ++m) {
            const int h = t + m * 256;
            float vtf = tanhf(acc[m]);
            float vtg = tanhf(acc[4 + m]);
            float vtk = tanhf(acc[8 + m]);
            tf[h] = vtf;
            tg[h] = vtg;
            tk[h] = vtk;
            sk[h] = 1.0f - vtk * vtk;           // sech^2 = d tanh/dz
        }
    }
    __syncthreads();

    // ---- layer 2 of all 3 MLPs: thread t = output channel i ----------------
    float af = bf2v[t];
    float ag = bg2v[t];
    float ak = bk2v[t];
    {
        const float4* rf = (const float4*)(Wf2 + t * H_);
        const float4* rg = (const float4*)(Wg2 + t * H_);
        const float4* rk = (const float4*)(Wk2 + t * H_);
        const float4* tf4 = (const float4*)tf;
        const float4* tg4 = (const float4*)tg;
        const float4* tk4 = (const float4*)tk;
        #pragma unroll 2
        for (int c = 0; c < 256; ++c) {
            float4 wf = rf[c], wg = rg[c], wk = rk[c];
            float4 vf = tf4[c];
            af += wf.x * vf.x + wf.y * vf.y + wf.z * vf.z + wf.w * vf.w;
            float4 vg = tg4[c];
            ag += wg.x * vg.x + wg.y * vg.y + wg.z * vg.z + wg.w * vg.w;
            float4 vk = tk4[c];
            ak += wk.x * vk.x + wk.y * vk.y + wk.z * vk.z + wk.w * vk.w;
        }
    }
    fo[t] = af;
    go[t] = ag;
    __syncthreads();

    // ---- vf = f_out @ Wk2, vg = g_out @ Wk2 ; then scale by sech^2 ---------
    // thread t owns h = 4t .. 4t+3 (float4, coalesced across threads)
    {
        float vf[4] = {0.f, 0.f, 0.f, 0.f};
        float vg[4] = {0.f, 0.f, 0.f, 0.f};
        const float* base = Wk2 + 4 * t;
        #pragma unroll 4
        for (int i = 0; i < N_; ++i) {
            float4 w = *(const float4*)(base + i * H_);
            float fv = fo[i], gv = go[i];
            vf[0] += w.x * fv; vf[1] += w.y * fv; vf[2] += w.z * fv; vf[3] += w.w * fv;
            vg[0] += w.x * gv; vg[1] += w.y * gv; vg[2] += w.z * gv; vg[3] += w.w * gv;
        }
        #pragma unroll
        for (int c = 0; c < 4; ++c) {
            sfv[4 * t + c] = sk[4 * t + c] * vf[c];
            sgv[4 * t + c] = sk[4 * t + c] * vg[c];
        }
    }
    __syncthreads();

    // ---- Jf[j] = sum_h sfv[h] * Wk1[h,j], JG likewise; thread t = j --------
    float jf = 0.f, jg = 0.f;
    {
        const float4* sf4p = (const float4*)sfv;
        const float4* sg4p = (const float4*)sgv;
        const float* col = Wk1 + t;
        #pragma unroll 4
        for (int c = 0; c < 256; ++c) {
            float4 s4 = sf4p[c];
            float4 g4 = sg4p[c];
            const int h = c * 4;
            float w0 = col[(h + 0) * N_];
            float w1 = col[(h + 1) * N_];
            float w2 = col[(h + 2) * N_];
            float w3 = col[(h + 3) * N_];
            jf += s4.x * w0 + s4.y * w1 + s4.z * w2 + s4.w * w3;
            jg += g4.x * w0 + g4.y * w1 + g4.z * w2 + g4.w * w3;
        }
    }

    // ---- reductions: ||k||^2, ||Jf||^2, <k, JG> ----------------------------
    float v0 = ak * ak;
    float v1 = jf * jf;
    float v2 = ak * jg;
    #pragma unroll
    for (int o = 32; o > 0; o >>= 1) {
        v0 += __shfl_xor(v0, o, 64);
        v1 += __shfl_xor(v1, o, 64);
        v2 += __shfl_xor(v2, o, 64);
    }
    const int wid = t >> 6;
    if ((t & 63) == 0) {
        red[wid * 3 + 0] = v0;
        red[wid * 3 + 1] = v1;
        red[wid * 3 + 2] = v2;
    }
    __syncthreads();
    const float kn2 = red[0] + red[3] + red[6] + red[9];
    const float jf2 = red[1] + red[4] + red[7] + red[10];
    const float kjg = red[2] + red[5] + red[8] + red[11];

    // c1 = ||Jf|| - 60*||k||^9 ; c2 = <k,JG> - 20*||k||^10  (= kn2^5)
    const float knorm = sqrtf(kn2);
    const float kn4 = kn2 * kn2;
    const float kn8 = kn4 * kn4;
    const float c1 = sqrtf(jf2) - 60.0f * kn8 * knorm;
    const float c2 = kjg - 20.0f * kn8 * kn2;
    const bool mask = (c1 > 1e-8f) || (c2 < -1e-8f);
    const float scale = mask ? 0.5f : 1.0f;

    out[b * N_ + t] = (af + ag) * scale;
}

extern "C" void kernel_launch(void* const* d_in, const int* in_sizes, int n_in,
                              void* d_out, int out_size, void* d_ws, size_t ws_size,
                              hipStream_t stream) {
    // setup_inputs order: t, x, Wf1, bf1, Wf2, bf2, Wg1, bg1, Wg2, bg2, Wk1, bk1, Wk2, bk2
    const float* x    = (const float*)d_in[1];
    const float* Wf1  = (const float*)d_in[2];
    const float* bf1v = (const float*)d_in[3];
    const float* Wf2  = (const float*)d_in[4];
    const float* bf2v = (const float*)d_in[5];
    const float* Wg1  = (const float*)d_in[6];
    const float* bg1v = (const float*)d_in[7];
    const float* Wg2  = (const float*)d_in[8];
    const float* bg2v = (const float*)d_in[9];
    const float* Wk1  = (const float*)d_in[10];
    const float* bk1v = (const float*)d_in[11];
    const float* Wk2  = (const float*)d_in[12];
    const float* bk2v = (const float*)d_in[13];

    manifold_fused<<<BS_, 256, 0, stream>>>(
        x, Wf1, bf1v, Wf2, bf2v, Wg1, bg1v, Wg2, bg2v,
        Wk1, bk1v, Wk2, bk2v, (float*)d_out);
}

// Round 3
// 143.058 us; speedup vs baseline: 2.2696x; 2.2696x over previous
//
#include <hip/hip_runtime.h>
#include <stdint.h>

#define N_ 256
#define H_ 1024
#define BS_ 128

// ---------------- workspace layout (floats) ----------------
// T   : [3][128][1024]  @ 0         (tanh outputs: tf, tg, tk)
// sk  : [128][1024]     @ 393216    (1 - tk^2)
// oacc: [3][128][256]   @ 524288    (fo, go, ko accumulators)
// sfv : [128][1024]     @ 622592
// sgv : [128][1024]     @ 753664
// jacc: [2][128][256]   @ 884736    (Jf, JG accumulators)
#define WS_T    0
#define WS_SK   393216
#define WS_OACC 524288
#define WS_SFV  622592
#define WS_SGV  753664
#define WS_JACC 884736
#define WS_FLOATS 950272   // 3,801,088 bytes

// ---- K1: layer1 + tanh (+ sech^2 for k). grid = 3*4*32 = 384 blocks ----
__global__ __launch_bounds__(256) void k1_layer1(
    const float* __restrict__ x,
    const float* __restrict__ Wf1, const float* __restrict__ bf1,
    const float* __restrict__ Wg1, const float* __restrict__ bg1,
    const float* __restrict__ Wk1, const float* __restrict__ bk1,
    float* __restrict__ T, float* __restrict__ sk)
{
    const int bx = blockIdx.x;          // m*128 + ht*32 + rt
    const int m  = bx >> 7;
    const int ht = (bx & 127) >> 5;
    const int rt = bx & 31;
    const int t  = threadIdx.x;
    const int r0 = rt * 4;
    const int h  = ht * 256 + t;

    const float* W  = (m == 0) ? Wf1 : (m == 1) ? Wg1 : Wk1;
    const float* b1 = (m == 0) ? bf1 : (m == 1) ? bg1 : bk1;

    __shared__ float xs[4][256];
    #pragma unroll
    for (int rr = 0; rr < 4; ++rr)
        xs[rr][t] = x[(r0 + rr) * N_ + t];
    __syncthreads();

    float acc[4];
    const float bv = b1[h];
    acc[0] = acc[1] = acc[2] = acc[3] = bv;
    const float4* w4 = (const float4*)(W + h * N_);
    #pragma unroll 4
    for (int c = 0; c < 64; ++c) {
        float4 w = w4[c];
        #pragma unroll
        for (int rr = 0; rr < 4; ++rr) {
            float4 a = ((const float4*)xs[rr])[c];
            acc[rr] += w.x * a.x + w.y * a.y + w.z * a.z + w.w * a.w;
        }
    }
    float* Tm = T + (m * BS_ + r0) * H_;
    #pragma unroll
    for (int rr = 0; rr < 4; ++rr) {
        float v = tanhf(acc[rr]);
        Tm[rr * H_ + h] = v;
        if (m == 2) sk[(r0 + rr) * H_ + h] = 1.0f - v * v;
    }
}

// ---- K2: layer2, k-split 4 with atomics. grid = 3*32*4 = 384 blocks ----
__global__ __launch_bounds__(256) void k2_layer2(
    const float* __restrict__ T,
    const float* __restrict__ Wf2, const float* __restrict__ bf2,
    const float* __restrict__ Wg2, const float* __restrict__ bg2,
    const float* __restrict__ Wk2, const float* __restrict__ bk2,
    float* __restrict__ oacc)
{
    const int bx = blockIdx.x;          // m*128 + rt*4 + ks
    const int m  = bx >> 7;
    const int rt = (bx & 127) >> 2;
    const int ks = bx & 3;
    const int t  = threadIdx.x;         // output channel i
    const int r0 = rt * 4;
    const int h0 = ks * 256;

    const float* W  = (m == 0) ? Wf2 : (m == 1) ? Wg2 : Wk2;
    const float* b2 = (m == 0) ? bf2 : (m == 1) ? bg2 : bk2;

    __shared__ float ts[4][256];
    #pragma unroll
    for (int rr = 0; rr < 4; ++rr)
        ts[rr][t] = T[(m * BS_ + r0 + rr) * H_ + h0 + t];
    __syncthreads();

    float acc[4];
    const float bv = (ks == 0) ? b2[t] : 0.0f;
    acc[0] = acc[1] = acc[2] = acc[3] = bv;
    const float4* w4 = (const float4*)(W + t * H_ + h0);
    #pragma unroll 4
    for (int c = 0; c < 64; ++c) {
        float4 w = w4[c];
        #pragma unroll
        for (int rr = 0; rr < 4; ++rr) {
            float4 a = ((const float4*)ts[rr])[c];
            acc[rr] += w.x * a.x + w.y * a.y + w.z * a.z + w.w * a.w;
        }
    }
    #pragma unroll
    for (int rr = 0; rr < 4; ++rr)
        atomicAdd(&oacc[(m * BS_ + r0 + rr) * N_ + t], acc[rr]);
}

// ---- K3: vf/vg = {fo,go} @ Wk2, scaled by sech^2. grid = 128*4 = 512 ----
__global__ __launch_bounds__(256) void k3_v(
    const float* __restrict__ Wk2,
    const float* __restrict__ oacc,
    const float* __restrict__ sk,
    float* __restrict__ sfv, float* __restrict__ sgv)
{
    const int bx = blockIdx.x;          // r*4 + ht
    const int r  = bx >> 2;
    const int ht = bx & 3;
    const int t  = threadIdx.x;
    const int h  = ht * 256 + t;

    __shared__ float fos[256], gos[256];
    fos[t] = oacc[r * N_ + t];
    gos[t] = oacc[(BS_ + r) * N_ + t];
    __syncthreads();

    float af = 0.f, ag = 0.f;
    const float* w = Wk2 + h;
    #pragma unroll 8
    for (int i = 0; i < 256; ++i) {
        float wv = w[i * H_];
        af += wv * fos[i];
        ag += wv * gos[i];
    }
    const float s = sk[r * H_ + h];
    sfv[r * H_ + h] = s * af;
    sgv[r * H_ + h] = s * ag;
}

// ---- K4: Jf/JG = {sfv,sgv} @ Wk1, k-split 4. grid = 128*4 = 512 ----
__global__ __launch_bounds__(256) void k4_j(
    const float* __restrict__ Wk1,
    const float* __restrict__ sfv, const float* __restrict__ sgv,
    float* __restrict__ jacc)
{
    const int bx = blockIdx.x;          // r*4 + ks
    const int r  = bx >> 2;
    const int ks = bx & 3;
    const int t  = threadIdx.x;         // output j
    const int h0 = ks * 256;

    __shared__ float sf[256], sg[256];
    sf[t] = sfv[r * H_ + h0 + t];
    sg[t] = sgv[r * H_ + h0 + t];
    __syncthreads();

    float aJf = 0.f, aJg = 0.f;
    const float* w = Wk1 + h0 * N_ + t;
    #pragma unroll 8
    for (int hh = 0; hh < 256; ++hh) {
        float wv = w[hh * N_];
        aJf += sf[hh] * wv;
        aJg += sg[hh] * wv;
    }
    atomicAdd(&jacc[r * N_ + t], aJf);
    atomicAdd(&jacc[(BS_ + r) * N_ + t], aJg);
}

// ---- K5: per-row reductions + mask + output. grid = 128 ----
__global__ __launch_bounds__(256) void k5_final(
    const float* __restrict__ oacc,
    const float* __restrict__ jacc,
    float* __restrict__ out)
{
    const int r = blockIdx.x;
    const int t = threadIdx.x;
    __shared__ float red[12];

    const float fo = oacc[r * N_ + t];
    const float go = oacc[(BS_ + r) * N_ + t];
    const float ko = oacc[(2 * BS_ + r) * N_ + t];
    const float jf = jacc[r * N_ + t];
    const float jg = jacc[(BS_ + r) * N_ + t];

    float v0 = ko * ko;
    float v1 = jf * jf;
    float v2 = ko * jg;
    #pragma unroll
    for (int o = 32; o > 0; o >>= 1) {
        v0 += __shfl_xor(v0, o, 64);
        v1 += __shfl_xor(v1, o, 64);
        v2 += __shfl_xor(v2, o, 64);
    }
    const int wid = t >> 6;
    if ((t & 63) == 0) {
        red[wid * 3 + 0] = v0;
        red[wid * 3 + 1] = v1;
        red[wid * 3 + 2] = v2;
    }
    __syncthreads();
    const float kn2 = red[0] + red[3] + red[6] + red[9];
    const float jf2 = red[1] + red[4] + red[7] + red[10];
    const float kjg = red[2] + red[5] + red[8] + red[11];

    const float knorm = sqrtf(kn2);
    const float kn4 = kn2 * kn2;
    const float kn8 = kn4 * kn4;
    const float c1 = sqrtf(jf2) - 60.0f * kn8 * knorm;
    const float c2 = kjg - 20.0f * kn8 * kn2;
    const bool mask = (c1 > 1e-8f) || (c2 < -1e-8f);
    const float scale = mask ? 0.5f : 1.0f;

    out[r * N_ + t] = (fo + go) * scale;
}

// ================= fallback: round-2 proven fused kernel =================
__global__ __launch_bounds__(256) void manifold_fused(
    const float* __restrict__ x,
    const float* __restrict__ Wf1, const float* __restrict__ bf1v,
    const float* __restrict__ Wf2, const float* __restrict__ bf2v,
    const float* __restrict__ Wg1, const float* __restrict__ bg1v,
    const float* __restrict__ Wg2, const float* __restrict__ bg2v,
    const float* __restrict__ Wk1, const float* __restrict__ bk1v,
    const float* __restrict__ Wk2, const float* __restrict__ bk2v,
    float* __restrict__ out)
{
    const int b = blockIdx.x;
    const int t = threadIdx.x;
    __shared__ float xs[N_];
    __shared__ float tf[H_], tg[H_], tk[H_], sk[H_];
    __shared__ float fo[N_], go[N_];
    __shared__ float sfv[H_], sgv[H_];
    __shared__ float red[12];

    xs[t] = x[b * N_ + t];
    __syncthreads();
    {
        float acc[12];
        const float4* rows[12];
        #pragma unroll
        for (int m = 0; m < 4; ++m) {
            const int h = t + m * 256;
            rows[m]     = (const float4*)(Wf1 + h * N_);
            rows[4 + m] = (const float4*)(Wg1 + h * N_);
            rows[8 + m] = (const float4*)(Wk1 + h * N_);
            acc[m] = bf1v[h]; acc[4 + m] = bg1v[h]; acc[8 + m] = bk1v[h];
        }
        const float4* xs4 = (const float4*)xs;
        #pragma unroll 2
        for (int c = 0; c < 64; ++c) {
            float4 a = xs4[c];
            #pragma unroll
            for (int r = 0; r < 12; ++r) {
                float4 w = rows[r][c];
                acc[r] += w.x * a.x + w.y * a.y + w.z * a.z + w.w * a.w;
            }
        }
        #pragma unroll
        for (int m = 0; m < 4; ++m) {
            const int h = t + m * 256;
            float vtf = tanhf(acc[m]);
            float vtg = tanhf(acc[4 + m]);
            float vtk = tanhf(acc[8 + m]);
            tf[h] = vtf; tg[h] = vtg; tk[h] = vtk; sk[h] = 1.0f - vtk * vtk;
        }
    }
    __syncthreads();
    float af = bf2v[t], ag = bg2v[t], ak = bk2v[t];
    {
        const float4* rf = (const float4*)(Wf2 + t * H_);
        const float4* rg = (const float4*)(Wg2 + t * H_);
        const float4* rk = (const float4*)(Wk2 + t * H_);
        #pragma unroll 2
        for (int c = 0; c < 256; ++c) {
            float4 wf = rf[c], wg = rg[c], wk = rk[c];
            float4 vf = ((const float4*)tf)[c];
            af += wf.x*vf.x + wf.y*vf.y + wf.z*vf.z + wf.w*vf.w;
            float4 vg = ((const float4*)tg)[c];
            ag += wg.x*vg.x + wg.y*vg.y + wg.z*vg.z + wg.w*vg.w;
            float4 vk = ((const float4*)tk)[c];
            ak += wk.x*vk.x + wk.y*vk.y + wk.z*vk.z + wk.w*vk.w;
        }
    }
    fo[t] = af; go[t] = ag;
    __syncthreads();
    {
        float vf[4] = {0.f,0.f,0.f,0.f}, vg[4] = {0.f,0.f,0.f,0.f};
        const float* base = Wk2 + 4 * t;
        #pragma unroll 4
        for (int i = 0; i < N_; ++i) {
            float4 w = *(const float4*)(base + i * H_);
            float fv = fo[i], gv = go[i];
            vf[0]+=w.x*fv; vf[1]+=w.y*fv; vf[2]+=w.z*fv; vf[3]+=w.w*fv;
            vg[0]+=w.x*gv; vg[1]+=w.y*gv; vg[2]+=w.z*gv; vg[3]+=w.w*gv;
        }
        #pragma unroll
        for (int c = 0; c < 4; ++c) {
            sfv[4*t+c] = sk[4*t+c]*vf[c];
            sgv[4*t+c] = sk[4*t+c]*vg[c];
        }
    }
    __syncthreads();
    float jf = 0.f, jg = 0.f;
    {
        const float* col = Wk1 + t;
        #pragma unroll 4
        for (int c = 0; c < 256; ++c) {
            float4 s4 = ((const float4*)sfv)[c];
            float4 g4 = ((const float4*)sgv)[c];
            const int h = c * 4;
            float w0 = col[(h+0)*N_], w1 = col[(h+1)*N_];
            float w2 = col[(h+2)*N_], w3 = col[(h+3)*N_];
            jf += s4.x*w0 + s4.y*w1 + s4.z*w2 + s4.w*w3;
            jg += g4.x*w0 + g4.y*w1 + g4.z*w2 + g4.w*w3;
        }
    }
    float v0 = ak*ak, v1 = jf*jf, v2 = ak*jg;
    #pragma unroll
    for (int o = 32; o > 0; o >>= 1) {
        v0 += __shfl_xor(v0, o, 64);
        v1 += __shfl_xor(v1, o, 64);
        v2 += __shfl_xor(v2, o, 64);
    }
    const int wid = t >> 6;
    if ((t & 63) == 0) {
        red[wid*3+0] = v0; red[wid*3+1] = v1; red[wid*3+2] = v2;
    }
    __syncthreads();
    const float kn2 = red[0]+red[3]+red[6]+red[9];
    const float jf2 = red[1]+red[4]+red[7]+red[10];
    const float kjg = red[2]+red[5]+red[8]+red[11];
    const float knorm = sqrtf(kn2);
    const float kn4 = kn2*kn2, kn8 = kn4*kn4;
    const float c1 = sqrtf(jf2) - 60.0f*kn8*knorm;
    const float c2 = kjg - 20.0f*kn8*kn2;
    const float scale = ((c1 > 1e-8f) || (c2 < -1e-8f)) ? 0.5f : 1.0f;
    out[b*N_+t] = (af+ag)*scale;
}

extern "C" void kernel_launch(void* const* d_in, const int* in_sizes, int n_in,
                              void* d_out, int out_size, void* d_ws, size_t ws_size,
                              hipStream_t stream) {
    const float* x    = (const float*)d_in[1];
    const float* Wf1  = (const float*)d_in[2];
    const float* bf1v = (const float*)d_in[3];
    const float* Wf2  = (const float*)d_in[4];
    const float* bf2v = (const float*)d_in[5];
    const float* Wg1  = (const float*)d_in[6];
    const float* bg1v = (const float*)d_in[7];
    const float* Wg2  = (const float*)d_in[8];
    const float* bg2v = (const float*)d_in[9];
    const float* Wk1  = (const float*)d_in[10];
    const float* bk1v = (const float*)d_in[11];
    const float* Wk2  = (const float*)d_in[12];
    const float* bk2v = (const float*)d_in[13];
    float* out = (float*)d_out;

    if (ws_size < (size_t)WS_FLOATS * sizeof(float)) {
        // not enough scratch: fall back to proven fused kernel
        manifold_fused<<<BS_, 256, 0, stream>>>(
            x, Wf1, bf1v, Wf2, bf2v, Wg1, bg1v, Wg2, bg2v,
            Wk1, bk1v, Wk2, bk2v, out);
        return;
    }

    float* ws   = (float*)d_ws;
    float* T    = ws + WS_T;
    float* sk   = ws + WS_SK;
    float* oacc = ws + WS_OACC;
    float* sfv  = ws + WS_SFV;
    float* sgv  = ws + WS_SGV;
    float* jacc = ws + WS_JACC;

    // zero the atomic accumulators (ws is poisoned 0xAA before every launch)
    hipMemsetAsync(oacc, 0, 3 * BS_ * N_ * sizeof(float), stream);
    hipMemsetAsync(jacc, 0, 2 * BS_ * N_ * sizeof(float), stream);

    k1_layer1<<<384, 256, 0, stream>>>(x, Wf1, bf1v, Wg1, bg1v, Wk1, bk1v, T, sk);
    k2_layer2<<<384, 256, 0, stream>>>(T, Wf2, bf2v, Wg2, bg2v, Wk2, bk2v, oacc);
    k3_v     <<<512, 256, 0, stream>>>(Wk2, oacc, sk, sfv, sgv);
    k4_j     <<<512, 256, 0, stream>>>(Wk1, sfv, sgv, jacc);
    k5_final <<<BS_, 256, 0, stream>>>(oacc, jacc, out);
}